// Round 8
// baseline (73.524 us; speedup 1.0000x reference)
//
#include <hip/hip_runtime.h>

// EqFrePBC: frequency-domain perturbation compensation. 2-node graph.
// Measured barrier costs on MI355X: cg grid.sync ~15us, fence+spin ~13us,
// sc1-flag worse (HBM traffic); kernel boundary ~free -> minimize node count.
// B=2, L=2048, N=2 modes, pairs = full 40x40 grid (n1,n2 in [-20,19]).
//   G[b,m,d]    = sum_n xf[b,m,n]*conj(xf[b,(m-(d-20))%L,n])
//   S2[b,d,l]   = sum_{n1i} w[n1i,d] * G[b,(l-(n1i-20))%L,d]
//   dfreq[b,n,l]= sum_d S2[b,d,l] * xf[b,n,(l-(d-20))%L]
// Bias is constant over freq -> IFFT puts it only at t=0, cropped out.
// K1 (64 blk x 512): per (b, 64-wide l-tile) block: redundant in-LDS fwd FFT of
//   both modes, then all-40-d S2+deltaf with register accumulation; df written
//   once per element (no atomics, no memset, no xf round-trip).
// K2 (4 blk x 512): radix-4 IFFT + epilogue.

#define L_FFT 2048
#define NB 2
#define NM 2
#define ND 40
#define CROP 20
#define LOUT 2008
#define NT 512
#define TILE 64        // l-tile width per K1 block
#define NGRP 8         // d-groups per block (64 lanes each)
#define GHALO 103      // TILE + 39 G entries per (group, iteration)

__device__ __forceinline__ float2 cmul(float2 a, float2 b) {
    return make_float2(a.x*b.x - a.y*b.y, a.x*b.y + a.y*b.x);
}
__device__ __forceinline__ float2 cmulc(float2 a, float2 b) {  // a * conj(b)
    return make_float2(a.x*b.x + a.y*b.y, a.y*b.x - a.x*b.y);
}

// tw[t] = exp(SIGN * i * 2*pi*t/2048), t in [0,512)
template<int SIGN>
__device__ void build_tw(float2* tw, int tid) {
    if (tid < 512) {
        float ang = (float)(SIGN * tid) * 3.0679615757712823e-03f;  // 2*pi/2048
        tw[tid] = make_float2(__cosf(ang), __sinf(ang));
    }
}

// Radix-4 Stockham FFT, 2048 pts, 512 threads (5 radix-4 stages + 1 radix-2).
// Result lands back in bufA. Internal syncs cover initial bufA writes.
template<int SIGN>
__device__ void fft2048_r4(float2* bufA, float2* bufB, const float2* tw, int tid) {
    float2* src = bufA;
    float2* dst = bufB;
    #pragma unroll
    for (int m = 1; m <= 256; m *= 4) {
        __syncthreads();
        int k2 = tid & (m - 1);
        int jm = tid - k2;                     // m*j2, < 512
        float2 A = src[tid];
        float2 C = src[tid + 512];
        float2 B = src[tid + 1024];
        float2 D = src[tid + 1536];
        float2 T0 = make_float2(A.x + B.x, A.y + B.y);
        float2 T1 = make_float2(A.x - B.x, A.y - B.y);
        float2 T2 = make_float2(C.x + D.x, C.y + D.y);
        float2 cd = make_float2(C.x - D.x, C.y - D.y);
        float2 T3 = (SIGN < 0) ? make_float2(cd.y, -cd.x)    // -i*(C-D)
                               : make_float2(-cd.y, cd.x);   // +i*(C-D)
        float2 w1 = tw[jm];
        float2 w2 = cmul(w1, w1);
        float2 w3 = cmul(w2, w1);
        int base = 4 * jm + k2;
        dst[base]         = make_float2(T0.x + T2.x, T0.y + T2.y);
        dst[base + m]     = cmul(make_float2(T1.x + T3.x, T1.y + T3.y), w1);
        dst[base + 2*m]   = cmul(make_float2(T0.x - T2.x, T0.y - T2.y), w2);
        dst[base + 3*m]   = cmul(make_float2(T1.x - T3.x, T1.y - T3.y), w3);
        float2* t = src; src = dst; dst = t;
    }
    __syncthreads();
    // final radix-2 stage, m=1024 (twiddle 1): src=bufB, writes dst=bufA
    #pragma unroll
    for (int it = 0; it < 2; ++it) {
        int q = tid + it * 512;
        float2 a = src[q];
        float2 b = src[q + 1024];
        dst[q]        = make_float2(a.x + b.x, a.y + b.y);
        dst[q + 1024] = make_float2(a.x - b.x, a.y - b.y);
    }
    __syncthreads();
}

// K1: redundant FFT + all-d S2 + deltaf, one block per (b, l-tile of 64).
__global__ __launch_bounds__(NT) void gs2_kernel(const float* __restrict__ xr,
                                                 const float* __restrict__ xi,
                                                 const float* __restrict__ wr,
                                                 const float* __restrict__ wi,
                                                 float2* __restrict__ df) {
    __shared__ float2 xs0[L_FFT];          // mode-0 spectrum (FFT in place)
    __shared__ float2 xs1[L_FFT];          // mode-1 spectrum
    __shared__ float2 tmp[L_FFT];          // FFT ping-pong
    __shared__ float2 tw[512];
    __shared__ float  wlr[1600], wli[1600];
    __shared__ float2 Gs[NGRP][GHALO];
    __shared__ float2 pr0[NT], pr1[NT];

    int blk = blockIdx.x;
    int b   = blk >> 5;            // 32 tiles per batch
    int l0  = (blk & 31) * TILE;
    int tid = threadIdx.x;

    // load both modes: x[b, t, n] at (b*2048+t)*2+n
    for (int t = tid; t < L_FFT; t += NT) {
        int gi = (b * L_FFT + t) * NM;
        xs0[t] = make_float2(xr[gi],     xi[gi]);
        xs1[t] = make_float2(xr[gi + 1], xi[gi + 1]);
    }
    // weights while FFT data loads settle
    for (int i = tid; i < 1600; i += NT) { wlr[i] = wr[i]; wli[i] = wi[i]; }
    build_tw<-1>(tw, tid);

    fft2048_r4<-1>(xs0, tmp, tw, tid);     // spectrum -> xs0
    fft2048_r4<-1>(xs1, tmp, tw, tid);     // spectrum -> xs1

    int grp = tid >> 6;            // d-group 0..7
    int lt  = tid & 63;            // l within tile
    int l   = l0 + lt;
    float2 acc0 = make_float2(0.f, 0.f);
    float2 acc1 = make_float2(0.f, 0.f);

    #pragma unroll
    for (int it = 0; it < 5; ++it) {
        int d  = it * NGRP + grp;
        int dd = d - 20;
        __syncthreads();           // protect Gs from previous iteration's readers
        // Gs[grp][j] = G[b, l0-19+j, d], j in [0,103)
        #pragma unroll
        for (int p = 0; p < 2; ++p) {
            int j = lt + p * 64;
            if (j < GHALO) {
                int m = l0 - 19 + j;
                float2 g0 = cmulc(xs0[m & (L_FFT-1)], xs0[(m - dd) & (L_FFT-1)]);
                float2 g1 = cmulc(xs1[m & (L_FFT-1)], xs1[(m - dd) & (L_FFT-1)]);
                Gs[grp][j] = make_float2(g0.x + g1.x, g0.y + g1.y);
            }
        }
        __syncthreads();
        // S2[l] = sum_{n1i} w[n1i,d] * Gs[grp][lt + 39 - n1i]
        float2 s2 = make_float2(0.f, 0.f);
        #pragma unroll
        for (int n1i = 0; n1i < ND; ++n1i) {
            float2 g = Gs[grp][lt + 39 - n1i];
            float wxr = wlr[n1i * ND + d], wxi = wli[n1i * ND + d];
            s2.x += wxr * g.x - wxi * g.y;
            s2.y += wxr * g.y + wxi * g.x;
        }
        // deltaf contribution: s2 * xf[b,n,l-dd]
        float2 xv0 = xs0[(l - dd) & (L_FFT-1)];
        float2 xv1 = xs1[(l - dd) & (L_FFT-1)];
        float2 c0 = cmul(s2, xv0);
        float2 c1 = cmul(s2, xv1);
        acc0.x += c0.x; acc0.y += c0.y;
        acc1.x += c1.x; acc1.y += c1.y;
    }
    // cross-group reduction: sum the 8 d-group partials per l, write df once
    pr0[tid] = acc0;
    pr1[tid] = acc1;
    __syncthreads();
    if (tid < 128) {
        int n = tid >> 6, lq = tid & 63;
        float2* pr = n ? pr1 : pr0;
        float2 s = make_float2(0.f, 0.f);
        #pragma unroll
        for (int g = 0; g < NGRP; ++g) {
            float2 v = pr[g * 64 + lq];
            s.x += v.x; s.y += v.y;
        }
        df[(b * 2 + n) * L_FFT + l0 + lq] = s;
    }
}

// K2: IFFT + epilogue. One block per (b,n).
__global__ __launch_bounds__(NT) void ifft_out_kernel(const float2* __restrict__ df,
                                                      const float* __restrict__ xr,
                                                      const float* __restrict__ xi,
                                                      const float* __restrict__ task,
                                                      float* __restrict__ out) {
    __shared__ float2 bufA[L_FFT];
    __shared__ float2 bufB[L_FFT];
    __shared__ float2 tw[512];
    int bn = blockIdx.x;            // b*2 + n
    int b = bn >> 1, n = bn & 1;
    int tid = threadIdx.x;
    const float2* dfreq = df + bn * L_FFT;
    #pragma unroll
    for (int it = 0; it < 4; ++it)
        bufA[tid + it * NT] = dfreq[tid + it * NT];
    build_tw<1>(tw, tid);
    fft2048_r4<1>(bufA, bufB, tw, tid);    // result in bufA
    float P = 1e-3f * __powf(10.f, task[b * 4] * 0.1f) * 0.5f;   // /N with N=2
    float scale = P * (1.0f / (float)L_FFT);                     // fold ifft 1/L
    for (int t = CROP + tid; t < L_FFT - CROP; t += NT) {
        int gi = (b * L_FFT + t) * NM + n;
        float2 dv = bufA[t];
        int oi = ((b * LOUT + (t - CROP)) * NM + n) * 2;
        out[oi]     = xr[gi] + dv.x * scale;
        out[oi + 1] = xi[gi] + dv.y * scale;
    }
}

extern "C" void kernel_launch(void* const* d_in, const int* in_sizes, int n_in,
                              void* d_out, int out_size, void* d_ws, size_t ws_size,
                              hipStream_t stream) {
    const float* xr   = (const float*)d_in[0];
    const float* xi   = (const float*)d_in[1];
    const float* task = (const float*)d_in[2];
    const float* wr   = (const float*)d_in[3];
    const float* wi   = (const float*)d_in[4];
    // d_in[5], d_in[6]: fc_br / fc_bi -- bias lands only at t=0 after IFFT, cropped out.
    float* out = (float*)d_out;

    float2* df = (float2*)d_ws;    // 8192 float2 [b*2+n][l], written once per element

    hipLaunchKernelGGL(gs2_kernel,      dim3(64), dim3(NT), 0, stream, xr, xi, wr, wi, df);
    hipLaunchKernelGGL(ifft_out_kernel, dim3(NB * NM), dim3(NT), 0, stream, df, xr, xi, task, out);
}

// Round 9
// 24.013 us; speedup vs baseline: 3.0618x; 3.0618x over previous
//
#include <hip/hip_runtime.h>

// EqFrePBC: frequency-domain perturbation compensation. 2-node graph.
// Measured: intra-kernel grid sync >=13us on MI355X (cg/fence-spin/sc1-flag all);
// kernel boundary ~free -> 2 nodes, fwd-FFT recomputed per block (redundant but
// wall-parallel). r8 regression root-caused to scratch spill (FETCH 28MB/WRITE 55MB
// at 1.7KB/thread): unroll bloat + 80KB LDS pinching the VGPR budget. This round:
// no outer unroll, 52KB LDS, weights via wave-uniform global loads, lb(512,2).
// B=2, L=2048, N=2 modes, pairs = full 40x40 grid (n1,n2 in [-20,19]).
//   G[b,m,d]    = sum_n xf[b,m,n]*conj(xf[b,(m-(d-20))%L,n])
//   S2[b,d,l]   = sum_{n1i} w[n1i,d] * G[b,(l-(n1i-20))%L,d]
//   dfreq[b,n,l]= sum_d S2[b,d,l] * xf[b,n,(l-(d-20))%L]
// Bias is constant over freq -> IFFT puts it only at t=0, cropped out.
// K1 (64 blk x 512): in-LDS fwd FFT of both modes + all-40-d S2 + deltaf,
//   df written once per element (no atomics, no memset).
// K2 (4 blk x 512): radix-4 IFFT + epilogue.

#define L_FFT 2048
#define NB 2
#define NM 2
#define ND 40
#define CROP 20
#define LOUT 2008
#define NT 512
#define TILE 64        // l-tile width per K1 block
#define NGRP 8         // d-groups per block (64 lanes each)
#define GHALO 103      // TILE + 39 G entries per (group, iteration)

__device__ __forceinline__ float2 cmul(float2 a, float2 b) {
    return make_float2(a.x*b.x - a.y*b.y, a.x*b.y + a.y*b.x);
}
__device__ __forceinline__ float2 cmulc(float2 a, float2 b) {  // a * conj(b)
    return make_float2(a.x*b.x + a.y*b.y, a.y*b.x - a.x*b.y);
}

// tw[t] = exp(SIGN * i * 2*pi*t/2048), t in [0,512)
template<int SIGN>
__device__ void build_tw(float2* tw, int tid) {
    if (tid < 512) {
        float ang = (float)(SIGN * tid) * 3.0679615757712823e-03f;  // 2*pi/2048
        tw[tid] = make_float2(__cosf(ang), __sinf(ang));
    }
}

// Radix-4 Stockham FFT, 2048 pts, 512 threads (5 radix-4 stages + 1 radix-2).
// Result lands back in bufA. Internal syncs cover initial bufA writes.
template<int SIGN>
__device__ void fft2048_r4(float2* bufA, float2* bufB, const float2* tw, int tid) {
    float2* src = bufA;
    float2* dst = bufB;
    #pragma unroll
    for (int m = 1; m <= 256; m *= 4) {
        __syncthreads();
        int k2 = tid & (m - 1);
        int jm = tid - k2;                     // m*j2, < 512
        float2 A = src[tid];
        float2 C = src[tid + 512];
        float2 B = src[tid + 1024];
        float2 D = src[tid + 1536];
        float2 T0 = make_float2(A.x + B.x, A.y + B.y);
        float2 T1 = make_float2(A.x - B.x, A.y - B.y);
        float2 T2 = make_float2(C.x + D.x, C.y + D.y);
        float2 cd = make_float2(C.x - D.x, C.y - D.y);
        float2 T3 = (SIGN < 0) ? make_float2(cd.y, -cd.x)    // -i*(C-D)
                               : make_float2(-cd.y, cd.x);   // +i*(C-D)
        float2 w1 = tw[jm];
        float2 w2 = cmul(w1, w1);
        float2 w3 = cmul(w2, w1);
        int base = 4 * jm + k2;
        dst[base]         = make_float2(T0.x + T2.x, T0.y + T2.y);
        dst[base + m]     = cmul(make_float2(T1.x + T3.x, T1.y + T3.y), w1);
        dst[base + 2*m]   = cmul(make_float2(T0.x - T2.x, T0.y - T2.y), w2);
        dst[base + 3*m]   = cmul(make_float2(T1.x - T3.x, T1.y - T3.y), w3);
        float2* t = src; src = dst; dst = t;
    }
    __syncthreads();
    // final radix-2 stage, m=1024 (twiddle 1): src=bufB, writes dst=bufA
    #pragma unroll
    for (int it = 0; it < 2; ++it) {
        int q = tid + it * 512;
        float2 a = src[q];
        float2 b = src[q + 1024];
        dst[q]        = make_float2(a.x + b.x, a.y + b.y);
        dst[q + 1024] = make_float2(a.x - b.x, a.y - b.y);
    }
    __syncthreads();
}

// K1: redundant FFT + all-d S2 + deltaf, one block per (b, l-tile of 64).
__global__ __launch_bounds__(NT, 2) void gs2_kernel(const float* __restrict__ xr,
                                                    const float* __restrict__ xi,
                                                    const float* __restrict__ wr,
                                                    const float* __restrict__ wi,
                                                    float2* __restrict__ df) {
    __shared__ float2 xs0[L_FFT];          // mode-0 spectrum (FFT in place)
    __shared__ float2 xs1[L_FFT];          // mode-1 spectrum
    __shared__ float2 scratch[L_FFT];      // FFT ping-pong, then Gs + pr
    __shared__ float2 tw[512];             // 52 KB total

    int blk = blockIdx.x;
    int b   = blk >> 5;            // 32 tiles per batch
    int l0  = (blk & 31) * TILE;
    int tid = threadIdx.x;

    // load both modes: x[b, t, n] at (b*2048+t)*2+n (contiguous pairs)
    for (int t = tid; t < L_FFT; t += NT) {
        int gi = (b * L_FFT + t) * NM;
        xs0[t] = make_float2(xr[gi],     xi[gi]);
        xs1[t] = make_float2(xr[gi + 1], xi[gi + 1]);
    }
    build_tw<-1>(tw, tid);

    fft2048_r4<-1>(xs0, scratch, tw, tid);     // spectrum -> xs0
    fft2048_r4<-1>(xs1, scratch, tw, tid);     // spectrum -> xs1

    // scratch re-purposed: Gs[8][103] then pr0/pr1[512]
    float2* Gs  = scratch;                 // NGRP*GHALO = 824
    float2* pr0 = scratch + NGRP * GHALO;  // 512
    float2* pr1 = pr0 + NT;                // 512  (total 1848 <= 2048)

    int grp = tid >> 6;            // d-group 0..7 (wave-uniform)
    int lt  = tid & 63;            // l within tile
    int l   = l0 + lt;
    float2 acc0 = make_float2(0.f, 0.f);
    float2 acc1 = make_float2(0.f, 0.f);

    #pragma unroll 1
    for (int it = 0; it < 5; ++it) {
        int d  = it * NGRP + grp;  // wave-uniform
        int dd = d - 20;
        __syncthreads();           // protect scratch from previous readers
        // Gs[grp][j] = G[b, l0-19+j, d], j in [0,103)
        #pragma unroll
        for (int p = 0; p < 2; ++p) {
            int j = lt + p * 64;
            if (j < GHALO) {
                int m = l0 - 19 + j;
                float2 g0 = cmulc(xs0[m & (L_FFT-1)], xs0[(m - dd) & (L_FFT-1)]);
                float2 g1 = cmulc(xs1[m & (L_FFT-1)], xs1[(m - dd) & (L_FFT-1)]);
                Gs[grp * GHALO + j] = make_float2(g0.x + g1.x, g0.y + g1.y);
            }
        }
        __syncthreads();
        // S2[l] = sum_{n1i} w[n1i,d] * Gs[grp][lt + 39 - n1i]
        // w loads are wave-uniform-address global loads (L1 broadcast).
        float2 s2 = make_float2(0.f, 0.f);
        #pragma unroll 4
        for (int n1i = 0; n1i < ND; ++n1i) {
            float2 g = Gs[grp * GHALO + lt + 39 - n1i];
            float wxr = wr[n1i * ND + d], wxi = wi[n1i * ND + d];
            s2.x += wxr * g.x - wxi * g.y;
            s2.y += wxr * g.y + wxi * g.x;
        }
        // deltaf contribution: s2 * xf[b,n,l-dd]
        float2 xv0 = xs0[(l - dd) & (L_FFT-1)];
        float2 xv1 = xs1[(l - dd) & (L_FFT-1)];
        float2 c0 = cmul(s2, xv0);
        float2 c1 = cmul(s2, xv1);
        acc0.x += c0.x; acc0.y += c0.y;
        acc1.x += c1.x; acc1.y += c1.y;
    }
    // cross-group reduction: sum the 8 d-group partials per l, write df once
    __syncthreads();               // Gs readers done before pr overwrites scratch
    pr0[tid] = acc0;
    pr1[tid] = acc1;
    __syncthreads();
    if (tid < 128) {
        int n = tid >> 6, lq = tid & 63;
        float2* pr = n ? pr1 : pr0;
        float2 s = make_float2(0.f, 0.f);
        #pragma unroll
        for (int g = 0; g < NGRP; ++g) {
            float2 v = pr[g * 64 + lq];
            s.x += v.x; s.y += v.y;
        }
        df[(b * 2 + n) * L_FFT + l0 + lq] = s;
    }
}

// K2: IFFT + epilogue. One block per (b,n).
__global__ __launch_bounds__(NT) void ifft_out_kernel(const float2* __restrict__ df,
                                                      const float* __restrict__ xr,
                                                      const float* __restrict__ xi,
                                                      const float* __restrict__ task,
                                                      float* __restrict__ out) {
    __shared__ float2 bufA[L_FFT];
    __shared__ float2 bufB[L_FFT];
    __shared__ float2 tw[512];
    int bn = blockIdx.x;            // b*2 + n
    int b = bn >> 1, n = bn & 1;
    int tid = threadIdx.x;
    const float2* dfreq = df + bn * L_FFT;
    #pragma unroll
    for (int it = 0; it < 4; ++it)
        bufA[tid + it * NT] = dfreq[tid + it * NT];
    build_tw<1>(tw, tid);
    fft2048_r4<1>(bufA, bufB, tw, tid);    // result in bufA
    float P = 1e-3f * __powf(10.f, task[b * 4] * 0.1f) * 0.5f;   // /N with N=2
    float scale = P * (1.0f / (float)L_FFT);                     // fold ifft 1/L
    for (int t = CROP + tid; t < L_FFT - CROP; t += NT) {
        int gi = (b * L_FFT + t) * NM + n;
        float2 dv = bufA[t];
        int oi = ((b * LOUT + (t - CROP)) * NM + n) * 2;
        out[oi]     = xr[gi] + dv.x * scale;
        out[oi + 1] = xi[gi] + dv.y * scale;
    }
}

extern "C" void kernel_launch(void* const* d_in, const int* in_sizes, int n_in,
                              void* d_out, int out_size, void* d_ws, size_t ws_size,
                              hipStream_t stream) {
    const float* xr   = (const float*)d_in[0];
    const float* xi   = (const float*)d_in[1];
    const float* task = (const float*)d_in[2];
    const float* wr   = (const float*)d_in[3];
    const float* wi   = (const float*)d_in[4];
    // d_in[5], d_in[6]: fc_br / fc_bi -- bias lands only at t=0 after IFFT, cropped out.
    float* out = (float*)d_out;

    float2* df = (float2*)d_ws;    // 8192 float2 [b*2+n][l], written once per element

    hipLaunchKernelGGL(gs2_kernel,      dim3(64), dim3(NT), 0, stream, xr, xi, wr, wi, df);
    hipLaunchKernelGGL(ifft_out_kernel, dim3(NB * NM), dim3(NT), 0, stream, df, xr, xi, task, out);
}

// Round 10
// 23.910 us; speedup vs baseline: 3.0751x; 1.0043x over previous
//
#include <hip/hip_runtime.h>

// EqFrePBC: frequency-domain perturbation compensation. 2-node graph.
// Measured on MI355X: intra-kernel grid sync >=13us (cg / fence-spin / sc1-flag);
// kernel boundary ~free -> minimal nodes, fwd-FFT recomputed per block (redundant
// but wall-parallel). r8's spill (FETCH 28MB/WRITE 55MB) fixed in r9 by killing
// unroll bloat + 80KB LDS. This round: dual-mode-per-barrier FFT (12 -> 6 barrier
// stages), inline __sinf/__cosf twiddles (no table; LDS = exactly 64KB), float2
// input loads.
// B=2, L=2048, N=2 modes, pairs = full 40x40 grid (n1,n2 in [-20,19]).
//   G[b,m,d]    = sum_n xf[b,m,n]*conj(xf[b,(m-(d-20))%L,n])
//   S2[b,d,l]   = sum_{n1i} w[n1i,d] * G[b,(l-(n1i-20))%L,d]
//   dfreq[b,n,l]= sum_d S2[b,d,l] * xf[b,n,(l-(d-20))%L]
// Bias is constant over freq -> IFFT puts it only at t=0, cropped out.
// K1 (64 blk x 512): in-LDS dual-mode fwd FFT + all-40-d S2 + deltaf,
//   df written once per element (no atomics, no memset).
// K2 (4 blk x 512): radix-4 IFFT + epilogue.

#define L_FFT 2048
#define NB 2
#define NM 2
#define ND 40
#define CROP 20
#define LOUT 2008
#define NT 512
#define TILE 64        // l-tile width per K1 block
#define NGRP 8         // d-groups per block (64 lanes each)
#define GHALO 103      // TILE + 39 G entries per (group, iteration)
#define ANGC 3.0679615757712823e-03f   // 2*pi/2048

__device__ __forceinline__ float2 cmul(float2 a, float2 b) {
    return make_float2(a.x*b.x - a.y*b.y, a.x*b.y + a.y*b.x);
}
__device__ __forceinline__ float2 cmulc(float2 a, float2 b) {  // a * conj(b)
    return make_float2(a.x*b.x + a.y*b.y, a.y*b.x - a.x*b.y);
}

// One radix-4 Stockham butterfly (inputs strided 512, outputs at 4jm+k2+{0,m,2m,3m}).
template<int SIGN>
__device__ __forceinline__ void r4_bfly(const float2* src, float2* dst, int tid,
                                        int m, float2 w1, float2 w2, float2 w3) {
    int k2 = tid & (m - 1);
    int jm = tid - k2;
    float2 A = src[tid];
    float2 C = src[tid + 512];
    float2 B = src[tid + 1024];
    float2 D = src[tid + 1536];
    float2 T0 = make_float2(A.x + B.x, A.y + B.y);
    float2 T1 = make_float2(A.x - B.x, A.y - B.y);
    float2 T2 = make_float2(C.x + D.x, C.y + D.y);
    float2 cd = make_float2(C.x - D.x, C.y - D.y);
    float2 T3 = (SIGN < 0) ? make_float2(cd.y, -cd.x)    // -i*(C-D)
                           : make_float2(-cd.y, cd.x);   // +i*(C-D)
    int base = 4 * jm + k2;
    dst[base]       = make_float2(T0.x + T2.x, T0.y + T2.y);
    dst[base + m]   = cmul(make_float2(T1.x + T3.x, T1.y + T3.y), w1);
    dst[base + 2*m] = cmul(make_float2(T0.x - T2.x, T0.y - T2.y), w2);
    dst[base + 3*m] = cmul(make_float2(T1.x - T3.x, T1.y - T3.y), w3);
}

// Dual-mode radix-4 Stockham FFT, 2048 pts, 512 threads: both modes' butterflies
// between the same barriers (6 barrier stages instead of 12). Results land back
// in x0 / x1. Internal syncs cover the initial x0/x1 writes.
template<int SIGN>
__device__ void fft2048_r4_dual(float2* x0, float2* t0, float2* x1, float2* t1, int tid) {
    float2 *s0 = x0, *d0 = t0, *s1 = x1, *d1 = t1;
    #pragma unroll
    for (int m = 1; m <= 256; m *= 4) {
        __syncthreads();
        int jm = tid - (tid & (m - 1));
        float ang = (float)(SIGN * jm) * ANGC;
        float sv = __sinf(ang), cv = __cosf(ang);
        float2 w1 = make_float2(cv, sv);
        float2 w2 = cmul(w1, w1);
        float2 w3 = cmul(w2, w1);
        r4_bfly<SIGN>(s0, d0, tid, m, w1, w2, w3);
        r4_bfly<SIGN>(s1, d1, tid, m, w1, w2, w3);
        float2* t;
        t = s0; s0 = d0; d0 = t;
        t = s1; s1 = d1; d1 = t;
    }
    __syncthreads();
    // final radix-2 stage, m=1024 (twiddle 1): src = t-buffers, dst = x-buffers
    #pragma unroll
    for (int it = 0; it < 2; ++it) {
        int q = tid + it * 512;
        float2 a0 = s0[q], b0 = s0[q + 1024];
        d0[q]        = make_float2(a0.x + b0.x, a0.y + b0.y);
        d0[q + 1024] = make_float2(a0.x - b0.x, a0.y - b0.y);
        float2 a1 = s1[q], b1 = s1[q + 1024];
        d1[q]        = make_float2(a1.x + b1.x, a1.y + b1.y);
        d1[q + 1024] = make_float2(a1.x - b1.x, a1.y - b1.y);
    }
    __syncthreads();
}

// Single-mode radix-4 FFT for K2 (table twiddles, proven r6/r9 path).
template<int SIGN>
__device__ void fft2048_r4(float2* bufA, float2* bufB, const float2* tw, int tid) {
    float2* src = bufA;
    float2* dst = bufB;
    #pragma unroll
    for (int m = 1; m <= 256; m *= 4) {
        __syncthreads();
        int jm = tid - (tid & (m - 1));
        float2 w1 = tw[jm];
        float2 w2 = cmul(w1, w1);
        float2 w3 = cmul(w2, w1);
        r4_bfly<SIGN>(src, dst, tid, m, w1, w2, w3);
        float2* t = src; src = dst; dst = t;
    }
    __syncthreads();
    #pragma unroll
    for (int it = 0; it < 2; ++it) {
        int q = tid + it * 512;
        float2 a = src[q];
        float2 b = src[q + 1024];
        dst[q]        = make_float2(a.x + b.x, a.y + b.y);
        dst[q + 1024] = make_float2(a.x - b.x, a.y - b.y);
    }
    __syncthreads();
}

template<int SIGN>
__device__ void build_tw(float2* tw, int tid) {
    if (tid < 512) {
        float ang = (float)(SIGN * tid) * ANGC;
        tw[tid] = make_float2(__cosf(ang), __sinf(ang));
    }
}

// K1: redundant dual-mode FFT + all-d S2 + deltaf, one block per (b, l-tile of 64).
__global__ __launch_bounds__(NT, 2) void gs2_kernel(const float* __restrict__ xr,
                                                    const float* __restrict__ xi,
                                                    const float* __restrict__ wr,
                                                    const float* __restrict__ wi,
                                                    float2* __restrict__ df) {
    __shared__ float2 xs0[L_FFT];          // mode-0 spectrum
    __shared__ float2 xs1[L_FFT];          // mode-1 spectrum
    __shared__ float2 scr0[L_FFT];         // ping-pong mode 0; then Gs + pr
    __shared__ float2 scr1[L_FFT];         // ping-pong mode 1      (64 KB total)

    int blk = blockIdx.x;
    int b   = blk >> 5;            // 32 tiles per batch
    int l0  = (blk & 31) * TILE;
    int tid = threadIdx.x;

    // x[b,t,n] at (b*2048+t)*2+n: modes adjacent -> float2 loads give both.
    const float2* xr2 = (const float2*)xr;
    const float2* xi2 = (const float2*)xi;
    for (int t = tid; t < L_FFT; t += NT) {
        float2 re = xr2[b * L_FFT + t];
        float2 im = xi2[b * L_FFT + t];
        xs0[t] = make_float2(re.x, im.x);
        xs1[t] = make_float2(re.y, im.y);
    }

    fft2048_r4_dual<-1>(xs0, scr0, xs1, scr1, tid);   // spectra -> xs0, xs1

    // scr re-purposed: Gs[8][103] then pr0/pr1[512] (1848 <= 2048 in scr0)
    float2* Gs  = scr0;                    // NGRP*GHALO = 824
    float2* pr0 = scr1;                    // 512
    float2* pr1 = scr1 + NT;               // 512

    int grp = tid >> 6;            // d-group 0..7 (wave-uniform)
    int lt  = tid & 63;            // l within tile
    int l   = l0 + lt;
    float2 acc0 = make_float2(0.f, 0.f);
    float2 acc1 = make_float2(0.f, 0.f);

    #pragma unroll 1
    for (int it = 0; it < 5; ++it) {
        int d  = it * NGRP + grp;  // wave-uniform
        int dd = d - 20;
        __syncthreads();           // protect Gs from previous iteration's readers
        #pragma unroll
        for (int p = 0; p < 2; ++p) {
            int j = lt + p * 64;
            if (j < GHALO) {
                int m = l0 - 19 + j;
                float2 g0 = cmulc(xs0[m & (L_FFT-1)], xs0[(m - dd) & (L_FFT-1)]);
                float2 g1 = cmulc(xs1[m & (L_FFT-1)], xs1[(m - dd) & (L_FFT-1)]);
                Gs[grp * GHALO + j] = make_float2(g0.x + g1.x, g0.y + g1.y);
            }
        }
        __syncthreads();
        // S2[l] = sum_{n1i} w[n1i,d] * Gs[grp][lt + 39 - n1i]; w loads wave-uniform.
        float2 s2 = make_float2(0.f, 0.f);
        #pragma unroll 4
        for (int n1i = 0; n1i < ND; ++n1i) {
            float2 g = Gs[grp * GHALO + lt + 39 - n1i];
            float wxr = wr[n1i * ND + d], wxi = wi[n1i * ND + d];
            s2.x += wxr * g.x - wxi * g.y;
            s2.y += wxr * g.y + wxi * g.x;
        }
        float2 xv0 = xs0[(l - dd) & (L_FFT-1)];
        float2 xv1 = xs1[(l - dd) & (L_FFT-1)];
        float2 c0 = cmul(s2, xv0);
        float2 c1 = cmul(s2, xv1);
        acc0.x += c0.x; acc0.y += c0.y;
        acc1.x += c1.x; acc1.y += c1.y;
    }
    // cross-group reduction: sum the 8 d-group partials per l, write df once
    __syncthreads();               // Gs readers done; pr shares scr1
    pr0[tid] = acc0;
    pr1[tid] = acc1;
    __syncthreads();
    if (tid < 128) {
        int n = tid >> 6, lq = tid & 63;
        float2* pr = n ? pr1 : pr0;
        float2 s = make_float2(0.f, 0.f);
        #pragma unroll
        for (int g = 0; g < NGRP; ++g) {
            float2 v = pr[g * 64 + lq];
            s.x += v.x; s.y += v.y;
        }
        df[(b * 2 + n) * L_FFT + l0 + lq] = s;
    }
}

// K2: IFFT + epilogue. One block per (b,n).
__global__ __launch_bounds__(NT) void ifft_out_kernel(const float2* __restrict__ df,
                                                      const float* __restrict__ xr,
                                                      const float* __restrict__ xi,
                                                      const float* __restrict__ task,
                                                      float* __restrict__ out) {
    __shared__ float2 bufA[L_FFT];
    __shared__ float2 bufB[L_FFT];
    __shared__ float2 tw[512];
    int bn = blockIdx.x;            // b*2 + n
    int b = bn >> 1, n = bn & 1;
    int tid = threadIdx.x;
    const float2* dfreq = df + bn * L_FFT;
    #pragma unroll
    for (int it = 0; it < 4; ++it)
        bufA[tid + it * NT] = dfreq[tid + it * NT];
    build_tw<1>(tw, tid);
    fft2048_r4<1>(bufA, bufB, tw, tid);    // result in bufA
    float P = 1e-3f * __powf(10.f, task[b * 4] * 0.1f) * 0.5f;   // /N with N=2
    float scale = P * (1.0f / (float)L_FFT);                     // fold ifft 1/L
    for (int t = CROP + tid; t < L_FFT - CROP; t += NT) {
        int gi = (b * L_FFT + t) * NM + n;
        float2 dv = bufA[t];
        int oi = ((b * LOUT + (t - CROP)) * NM + n) * 2;
        out[oi]     = xr[gi] + dv.x * scale;
        out[oi + 1] = xi[gi] + dv.y * scale;
    }
}

extern "C" void kernel_launch(void* const* d_in, const int* in_sizes, int n_in,
                              void* d_out, int out_size, void* d_ws, size_t ws_size,
                              hipStream_t stream) {
    const float* xr   = (const float*)d_in[0];
    const float* xi   = (const float*)d_in[1];
    const float* task = (const float*)d_in[2];
    const float* wr   = (const float*)d_in[3];
    const float* wi   = (const float*)d_in[4];
    // d_in[5], d_in[6]: fc_br / fc_bi -- bias lands only at t=0 after IFFT, cropped out.
    float* out = (float*)d_out;

    float2* df = (float2*)d_ws;    // 8192 float2 [b*2+n][l], written once per element

    hipLaunchKernelGGL(gs2_kernel,      dim3(64), dim3(NT), 0, stream, xr, xi, wr, wi, df);
    hipLaunchKernelGGL(ifft_out_kernel, dim3(NB * NM), dim3(NT), 0, stream, df, xr, xi, task, out);
}